// Round 19
// baseline (109.084 us; speedup 1.0000x reference)
//
#include <hip/hip_runtime.h>

#define BS 16
#define NNODES 20000
#define CIN 32
#define SEQ 9
#define COUT 64
#define KTOT 288
#define MPOOL 5000
#define NNZ 20000

#define H_BYTES   40960000ULL   // hT [8][20000][64] u32  (= [g][node][oc][2bl] bf16)
#define XB_BYTES  20480000ULL   // xbT2 [8][20000][2][32] bf16
#define WF_BYTES  36864ULL      // wf [SEQ*4][512] bf16 fragment-ordered
#define CV_BYTES  (NNZ * 8ULL)  // packed (col, val)
#define START_BYTES ((MPOOL + 1) * 4ULL)

#define XBLK (NNODES / 4)        // 5000 transpose blocks
#define WBLK 9
#define NTILE8 (313 * 8)         // gemm blocks

typedef __attribute__((ext_vector_type(8))) short bf16x8;
typedef __attribute__((ext_vector_type(4))) float f32x4;

static __device__ __forceinline__ unsigned short f2bf(float f) {
  unsigned u = __float_as_uint(f);
  u += 0x7FFF + ((u >> 16) & 1);   // RNE
  return (unsigned short)(u >> 16);
}
static __device__ __forceinline__ float bf2f(unsigned short s) {
  return __uint_as_float(((unsigned)s) << 16);
}
static __device__ __forceinline__ unsigned cvt_pk_bf16(float lo, float hi) {
  unsigned r;
  asm("v_cvt_pk_bf16_f32 %0, %1, %2" : "=v"(r) : "v"(lo), "v"(hi));
  return r;   // lo in [15:0], hi in [31:16], RNE
}

// ---- prep: block 0 = CSR build (in-LDS, hidden under transpose blocks);
//      blocks 1..5000 = x transpose; 5001..5009 = weight fragments ----
__global__ __launch_bounds__(256) void prep_kernel(const float* __restrict__ x,
                                                   const float* __restrict__ weight,
                                                   unsigned short* __restrict__ xbT2,
                                                   unsigned short* __restrict__ wf,
                                                   const int* __restrict__ trows,
                                                   const int* __restrict__ tcols,
                                                   const float* __restrict__ tvals,
                                                   int* __restrict__ start,
                                                   int2* __restrict__ cvp,
                                                   int do_csr) {
  __shared__ int lcnt[MPOOL];   // 20 KB (only block 0 uses; 7 blocks/CU, BW-bound ok)
  __shared__ int part[256];

  const int id = blockIdx.x;
  const int tid = threadIdx.x;

  if (id == 0) {
    if (!do_csr) return;
    // hist -> scan -> reorder, all in LDS (no global cnt/cursor, no zero pass)
    for (int i = tid; i < MPOOL; i += 256) lcnt[i] = 0;
    __syncthreads();
    for (int k = tid; k < NNZ; k += 256) atomicAdd(&lcnt[trows[k]], 1);
    __syncthreads();
    int local[20];
    int s = 0;
    const int base = tid * 20;
#pragma unroll
    for (int j = 0; j < 20; ++j) {
      const int i = base + j;
      local[j] = s;
      s += (i < MPOOL) ? lcnt[i] : 0;
    }
    part[tid] = s;
    __syncthreads();
    for (int off = 1; off < 256; off <<= 1) {
      const int v = (tid >= off) ? part[tid - off] : 0;
      __syncthreads();
      part[tid] += v;
      __syncthreads();
    }
    const int excl = (tid == 0) ? 0 : part[tid - 1];
    __syncthreads();
#pragma unroll
    for (int j = 0; j < 20; ++j) {
      const int i = base + j;
      if (i < MPOOL) {
        const int sv = excl + local[j];
        start[i] = sv;
        lcnt[i] = sv;   // becomes cursor
      }
    }
    if (tid == 255) start[MPOOL] = NNZ;
    __syncthreads();
    for (int k = tid; k < NNZ; k += 256) {
      const int pos = atomicAdd(&lcnt[trows[k]], 1);
      cvp[pos] = make_int2(tcols[k], __float_as_int(tvals[k]));
    }
  } else if (id <= XBLK) {
    const int W = (id - 1) * 4 + (tid >> 6);     // global wave 0..19999
    const int lane = tid & 63;
    const unsigned b = (unsigned)W / 1250u;      // batch 0..15
    const unsigned tile = (unsigned)W % 1250u;
    const int n = (int)tile * 16 + (lane >> 2);
    const int c8 = (lane & 3) * 8;
    const float* src = x + ((size_t)b * NNODES + n) * CIN + c8;   // 2KB/wave contiguous
    const float4 u0 = ((const float4*)src)[0];
    const float4 u1 = ((const float4*)src)[1];
    uint4 p;
    p.x = (unsigned)f2bf(u0.x) | ((unsigned)f2bf(u0.y) << 16);
    p.y = (unsigned)f2bf(u0.z) | ((unsigned)f2bf(u0.w) << 16);
    p.z = (unsigned)f2bf(u1.x) | ((unsigned)f2bf(u1.y) << 16);
    p.w = (unsigned)f2bf(u1.z) | ((unsigned)f2bf(u1.w) << 16);
    const int g = (int)(b >> 1), bl = (int)(b & 1);
    *(uint4*)&xbT2[((size_t)g * NNODES + n) * 64 + bl * 32 + c8] = p;
  } else {
    // wf[(kk*4+o)*512 + lhi*128 + l16*8 + e] = W[o*16+l16][kk*32+lhi*8+e]
    const int t = (id - XBLK - 1) * 256 + tid;
    if (t < SEQ * 4 * 64) {
      const int f0 = t * 8;
      const int blk = f0 >> 9;
      const int inb = f0 & 511;
      const int lhi = inb >> 7;
      const int l16 = (inb >> 3) & 15;
      const int kk = blk >> 2, o = blk & 3;
      const float* src = weight + (size_t)(o * 16 + l16) * KTOT + kk * 32 + lhi * 8;
      const float4 u0 = ((const float4*)src)[0];
      const float4 u1 = ((const float4*)src)[1];
      uint4 p;
      p.x = (unsigned)f2bf(u0.x) | ((unsigned)f2bf(u0.y) << 16);
      p.y = (unsigned)f2bf(u0.z) | ((unsigned)f2bf(u0.w) << 16);
      p.z = (unsigned)f2bf(u1.x) | ((unsigned)f2bf(u1.y) << 16);
      p.w = (unsigned)f2bf(u1.z) | ((unsigned)f2bf(u1.w) << 16);
      *(uint4*)&wf[f0] = p;
    }
  }
}

// ---- gemm+elu: EXACT R17 kernel (measured-good). Per-XCD batch-slice, bid&7=g. ----
__global__ __launch_bounds__(512, 8) void gemm_elu_kernel(
    const unsigned short* __restrict__ xbT2,  // [8][NNODES][2][32] bf16
    const int* __restrict__ indices,          // [NNODES][SEQ]
    const unsigned short* __restrict__ wf,    // [SEQ*4][512] bf16 fragment-ordered
    const float* __restrict__ bias,
    unsigned* __restrict__ hT)                // [8][NNODES][64] u32 (2 bf16 each)
{
  __shared__ unsigned short wlds[SEQ * 4 * 512];   // 36864 B = 2304 uint4
  __shared__ int idx_lds[64 * SEQ];                // 2304 B

  const int tid = threadIdx.x;
  const int g = blockIdx.x & 7;
  const int n0 = (blockIdx.x >> 3) * 64;

  {
    const uint4* src = (const uint4*)wf;
    uint4* dst = (uint4*)wlds;
    for (int i = tid; i < (SEQ * 4 * 512 * 2) / 16; i += 512)   // 2304 uint4, guarded
      dst[i] = src[i];
  }
  for (int i = tid; i < 64 * SEQ; i += 512) {
    const int gidx = n0 * SEQ + i;
    idx_lds[i] = (gidx < NNODES * SEQ) ? indices[gidx] : 0;
  }
  __syncthreads();

  const int wv = tid >> 6;
  const int lane = tid & 63;
  const int l16 = lane & 15;
  const int lhi = lane >> 4;
  const int n0w = n0 + wv * 8;          // wave owns 8 nodes x 2 batches
  if (n0w >= NNODES) return;

  const unsigned short* __restrict__ xg = xbT2 + (size_t)g * NNODES * 64;
  const int moff = (l16 & 1) * 32 + lhi * 8;       // bl*32 + k-slice (bf16 units)
  const int boff = lane * 8;
  const int idxbase = (wv * 8 + (l16 >> 1)) * SEQ; // per-lane node's index row

  f32x4 acc[4];
#pragma unroll
  for (int o = 0; o < 4; ++o) {
    f32x4 z = {0.f, 0.f, 0.f, 0.f};
    acc[o] = z;
  }

#pragma unroll
  for (int kk = 0; kk < SEQ; ++kk) {
    const int gi = idx_lds[idxbase + kk];          // per-lane (8 distinct/wave)
    const bf16x8 af = *(const bf16x8*)&xg[(size_t)gi * 64 + moff];
    const bf16x8 b0 = *(const bf16x8*)&wlds[(kk * 4 + 0) * 512 + boff];
    const bf16x8 b1 = *(const bf16x8*)&wlds[(kk * 4 + 1) * 512 + boff];
    const bf16x8 b2 = *(const bf16x8*)&wlds[(kk * 4 + 2) * 512 + boff];
    const bf16x8 b3 = *(const bf16x8*)&wlds[(kk * 4 + 3) * 512 + boff];
    acc[0] = __builtin_amdgcn_mfma_f32_16x16x32_bf16(af, b0, acc[0], 0, 0, 0);
    acc[1] = __builtin_amdgcn_mfma_f32_16x16x32_bf16(af, b1, acc[1], 0, 0, 0);
    acc[2] = __builtin_amdgcn_mfma_f32_16x16x32_bf16(af, b2, acc[2], 0, 0, 0);
    acc[3] = __builtin_amdgcn_mfma_f32_16x16x32_bf16(af, b3, acc[3], 0, 0, 0);
  }

  // epilogue: D row m = lhi*4+reg -> node = n0w + (m>>1), bl = m&1.
  unsigned* __restrict__ hg = hT + (size_t)g * NNODES * 64;
  const int nA = n0w + lhi * 2;
#pragma unroll
  for (int o = 0; o < 4; ++o) {
    const int oc = o * 16 + l16;
    const float bv = bias[oc];
    float v0 = acc[o][0] + bv, v1 = acc[o][1] + bv;
    float v2 = acc[o][2] + bv, v3 = acc[o][3] + bv;
    v0 = v0 > 0.f ? v0 : (__expf(v0) - 1.f);
    v1 = v1 > 0.f ? v1 : (__expf(v1) - 1.f);
    v2 = v2 > 0.f ? v2 : (__expf(v2) - 1.f);
    v3 = v3 > 0.f ? v3 : (__expf(v3) - 1.f);
    hg[(size_t)nA * 64 + oc]       = cvt_pk_bf16(v0, v1);
    hg[(size_t)(nA + 1) * 64 + oc] = cvt_pk_bf16(v2, v3);
  }
}

// ---- pool: wave per row; per entry 8x 256B-contiguous slice reads ----
__global__ __launch_bounds__(256) void pool_kernel(
    const unsigned* __restrict__ hT,        // [8][NNODES][64] u32
    const int* __restrict__ start,
    const int2* __restrict__ cvp,
    float* __restrict__ out)                // [BS][MPOOL][COUT]
{
  const int r = blockIdx.x * 4 + (threadIdx.x >> 6);
  const int lane = threadIdx.x & 63;       // lane = oc

  float acc[16];
#pragma unroll
  for (int b = 0; b < 16; ++b) acc[b] = 0.f;

  const int s = start[r], e = start[r + 1];
  int2 cv = (s < e) ? cvp[s] : make_int2(0, 0);
  for (int j = s; j < e; ++j) {
    const int2 cvn = (j + 1 < e) ? cvp[j + 1] : make_int2(0, 0);
    const int c = cv.x;
    const float v = __int_as_float(cv.y);
#pragma unroll
    for (int g = 0; g < 8; ++g) {
      const unsigned u = hT[((size_t)g * NNODES + c) * 64 + lane];
      acc[2 * g]     += v * bf2f((unsigned short)(u & 0xffff));
      acc[2 * g + 1] += v * bf2f((unsigned short)(u >> 16));
    }
    cv = cvn;
  }
#pragma unroll
  for (int b = 0; b < 16; ++b)
    out[((size_t)b * MPOOL + r) * COUT + lane] = acc[b];
}

// ---- fallback atomic scatter (small ws) ----
__global__ __launch_bounds__(256) void scatter_kernel(
    const unsigned* __restrict__ hT,
    const int* __restrict__ rows,
    const int* __restrict__ cols,
    const float* __restrict__ vals,
    float* __restrict__ out)
{
  const int gw = (int)((blockIdx.x * blockDim.x + threadIdx.x) >> 6);
  const int lane = threadIdx.x & 63;
  const int nw = (int)((gridDim.x * blockDim.x) >> 6);
  for (int t = gw; t < NNZ * BS; t += nw) {
    const int k = t >> 4;
    const int b = t & 15;
    const unsigned u = hT[((size_t)(b >> 1) * NNODES + cols[k]) * 64 + lane];
    const float hv = bf2f((unsigned short)((b & 1) ? (u >> 16) : (u & 0xffff)));
    atomicAdd(&out[((size_t)b * MPOOL + rows[k]) * COUT + lane], hv * vals[k]);
  }
}

extern "C" void kernel_launch(void* const* d_in, const int* in_sizes, int n_in,
                              void* d_out, int out_size, void* d_ws, size_t ws_size,
                              hipStream_t stream) {
  const float* x       = (const float*)d_in[0];
  const int*   indices = (const int*)d_in[1];
  const float* weight  = (const float*)d_in[2];
  const float* bias    = (const float*)d_in[3];
  const int*   trows   = (const int*)d_in[4];
  const int*   tcols   = (const int*)d_in[5];
  const float* tvals   = (const float*)d_in[6];
  float* out = (float*)d_out;

  char* w = (char*)d_ws;
  unsigned* hT         = (unsigned*)w;
  unsigned short* xbT2 = (unsigned short*)(w + H_BYTES);
  unsigned short* wf   = (unsigned short*)(w + H_BYTES + XB_BYTES);
  int2* cvp  = (int2*)(w + H_BYTES + XB_BYTES + WF_BYTES);
  int* start = (int*)(w + H_BYTES + XB_BYTES + WF_BYTES + CV_BYTES);

  const bool big_ws =
      (ws_size >= H_BYTES + XB_BYTES + WF_BYTES + CV_BYTES + START_BYTES);

  // block 0 = CSR build (hidden under the 5009 streaming blocks); 3 dispatches total
  prep_kernel<<<1 + XBLK + WBLK, 256, 0, stream>>>(x, weight, xbT2, wf,
                                                   trows, tcols, tvals,
                                                   start, cvp, big_ws ? 1 : 0);

  gemm_elu_kernel<<<NTILE8, 512, 0, stream>>>(xbT2, indices, wf, bias, hT);

  if (big_ws) {
    pool_kernel<<<MPOOL / 4, 256, 0, stream>>>(hT, start, cvp, out);
  } else {
    hipMemsetAsync(d_out, 0, (size_t)out_size * sizeof(float), stream);
    scatter_kernel<<<4096, 256, 0, stream>>>(hT, trows, tcols, tvals, out);
  }
}

// Round 20
// 61.473 us; speedup vs baseline: 1.7745x; 1.7745x over previous
//
#include <hip/hip_runtime.h>

#define BS 16
#define NNODES 20000
#define CIN 32
#define SEQ 9
#define COUT 64
#define KTOT 288
#define MPOOL 5000
#define NNZ 20000

#define H_BYTES   40960000ULL   // hT [8][20000][64] u32  (= [g][node][oc][2bl] bf16)
#define XB_BYTES  20480000ULL   // xbT2 [8][20000][2][32] bf16
#define WF_BYTES  36864ULL      // wf [SEQ*4][512] bf16 fragment-ordered
#define CV_BYTES  (NNZ * 8ULL)  // packed (col, val)
#define START_BYTES ((MPOOL + 1) * 4ULL)
#define CNTCUR_BYTES (2ULL * MPOOL * 4ULL)

#define XBLK (NNODES / 4)        // 5000 blocks: x transpose
#define WBLK 9
#define ZBLK 10

typedef __attribute__((ext_vector_type(8))) short bf16x8;
typedef __attribute__((ext_vector_type(4))) float f32x4;

static __device__ __forceinline__ unsigned short f2bf(float f) {
  unsigned u = __float_as_uint(f);
  u += 0x7FFF + ((u >> 16) & 1);   // RNE
  return (unsigned short)(u >> 16);
}
static __device__ __forceinline__ float bf2f(unsigned short s) {
  return __uint_as_float(((unsigned)s) << 16);
}
static __device__ __forceinline__ unsigned cvt_pk_bf16(float lo, float hi) {
  unsigned r;
  asm("v_cvt_pk_bf16_f32 %0, %1, %2" : "=v"(r) : "v"(lo), "v"(hi));
  return r;   // lo in [15:0], hi in [31:16], RNE
}

// ---- prep: x[b][n][c] f32 -> xbT2[b>>1][n][b&1][c] bf16 (coalesced read),
//      weight fragments, zero cnt+cursor ----
__global__ __launch_bounds__(256) void prep_kernel(const float* __restrict__ x,
                                                   const float* __restrict__ weight,
                                                   unsigned short* __restrict__ xbT2,
                                                   unsigned short* __restrict__ wf,
                                                   int* __restrict__ cntcur) {
  const int id = blockIdx.x;
  if (id < XBLK) {
    const int W = id * 4 + (threadIdx.x >> 6);   // global wave 0..19999
    const int lane = threadIdx.x & 63;
    const unsigned b = (unsigned)W / 1250u;      // batch 0..15
    const unsigned tile = (unsigned)W % 1250u;
    const int n = (int)tile * 16 + (lane >> 2);
    const int c8 = (lane & 3) * 8;
    const float* src = x + ((size_t)b * NNODES + n) * CIN + c8;   // 2KB/wave contiguous
    const float4 u0 = ((const float4*)src)[0];
    const float4 u1 = ((const float4*)src)[1];
    uint4 p;
    p.x = (unsigned)f2bf(u0.x) | ((unsigned)f2bf(u0.y) << 16);
    p.y = (unsigned)f2bf(u0.z) | ((unsigned)f2bf(u0.w) << 16);
    p.z = (unsigned)f2bf(u1.x) | ((unsigned)f2bf(u1.y) << 16);
    p.w = (unsigned)f2bf(u1.z) | ((unsigned)f2bf(u1.w) << 16);
    const int g = (int)(b >> 1), bl = (int)(b & 1);
    *(uint4*)&xbT2[((size_t)g * NNODES + n) * 64 + bl * 32 + c8] = p;
  } else if (id < XBLK + WBLK) {
    // wf[(kk*4+o)*512 + lhi*128 + l16*8 + e] = W[o*16+l16][kk*32+lhi*8+e]
    const int t = (id - XBLK) * 256 + threadIdx.x;
    if (t < SEQ * 4 * 64) {
      const int f0 = t * 8;
      const int blk = f0 >> 9;
      const int inb = f0 & 511;
      const int lhi = inb >> 7;
      const int l16 = (inb >> 3) & 15;
      const int kk = blk >> 2, o = blk & 3;
      const float* src = weight + (size_t)(o * 16 + l16) * KTOT + kk * 32 + lhi * 8;
      const float4 u0 = ((const float4*)src)[0];
      const float4 u1 = ((const float4*)src)[1];
      uint4 p;
      p.x = (unsigned)f2bf(u0.x) | ((unsigned)f2bf(u0.y) << 16);
      p.y = (unsigned)f2bf(u0.z) | ((unsigned)f2bf(u0.w) << 16);
      p.z = (unsigned)f2bf(u1.x) | ((unsigned)f2bf(u1.y) << 16);
      p.w = (unsigned)f2bf(u1.z) | ((unsigned)f2bf(u1.w) << 16);
      *(uint4*)&wf[f0] = p;
    }
  } else {
    const int base = (id - XBLK - WBLK) * 1024 + threadIdx.x;
#pragma unroll
    for (int j = 0; j < 4; ++j) {
      const int i = base + j * 256;
      if (i < 2 * MPOOL) cntcur[i] = 0;
    }
  }
}

// ---- CSR build, multi-block ----
__global__ __launch_bounds__(256) void hist_kernel(const int* __restrict__ rows,
                                                   int* __restrict__ cnt) {
  const int k = blockIdx.x * 256 + threadIdx.x;
  if (k < NNZ) atomicAdd(&cnt[rows[k]], 1);
}

__global__ __launch_bounds__(256) void scan_kernel(const int* __restrict__ cnt,
                                                   int* __restrict__ start) {
  __shared__ int part[256];
  const int t = threadIdx.x;
  const int base = t * 20;
  int local[20];
  int s = 0;
#pragma unroll
  for (int j = 0; j < 20; ++j) {
    const int i = base + j;
    local[j] = s;
    s += (i < MPOOL) ? cnt[i] : 0;
  }
  part[t] = s;
  __syncthreads();
  for (int off = 1; off < 256; off <<= 1) {
    const int v = (t >= off) ? part[t - off] : 0;
    __syncthreads();
    part[t] += v;
    __syncthreads();
  }
  const int excl = (t == 0) ? 0 : part[t - 1];
#pragma unroll
  for (int j = 0; j < 20; ++j) {
    const int i = base + j;
    if (i < MPOOL) start[i] = excl + local[j];
  }
  if (t == 255) start[MPOOL] = NNZ;
}

__global__ __launch_bounds__(256) void reorder_kernel(const int* __restrict__ rows,
                                                      const int* __restrict__ cols,
                                                      const float* __restrict__ vals,
                                                      const int* __restrict__ start,
                                                      int* __restrict__ cursor,
                                                      int2* __restrict__ cvp) {
  const int k = blockIdx.x * 256 + threadIdx.x;
  if (k < NNZ) {
    const int r = rows[k];
    const int pos = start[r] + atomicAdd(&cursor[r], 1);
    cvp[pos] = make_int2(cols[k], __float_as_int(vals[k]));
  }
}

// ---- gemm+elu: per-XCD batch-slice. bid&7 = g (maps to XCD via %8 round-robin).
//      Wave M=16 = 8 nodes x 2 batches; gathers hit the XCD-local 2.56MB slice in L2. ----
__global__ __launch_bounds__(512, 8) void gemm_elu_kernel(
    const unsigned short* __restrict__ xbT2,  // [8][NNODES][2][32] bf16
    const int* __restrict__ indices,          // [NNODES][SEQ]
    const unsigned short* __restrict__ wf,    // [SEQ*4][512] bf16 fragment-ordered
    const float* __restrict__ bias,
    unsigned* __restrict__ hT)                // [8][NNODES][64] u32 (2 bf16 each)
{
  __shared__ unsigned short wlds[SEQ * 4 * 512];   // 36864 B = 2304 uint4
  __shared__ int idx_lds[64 * SEQ];                // 2304 B

  const int tid = threadIdx.x;
  const int g = blockIdx.x & 7;
  const int n0 = (blockIdx.x >> 3) * 64;

  {
    const uint4* src = (const uint4*)wf;
    uint4* dst = (uint4*)wlds;
    for (int i = tid; i < (SEQ * 4 * 512 * 2) / 16; i += 512)   // 2304 uint4, guarded
      dst[i] = src[i];
  }
  for (int i = tid; i < 64 * SEQ; i += 512) {
    const int gidx = n0 * SEQ + i;
    idx_lds[i] = (gidx < NNODES * SEQ) ? indices[gidx] : 0;
  }
  __syncthreads();

  const int wv = tid >> 6;
  const int lane = tid & 63;
  const int l16 = lane & 15;
  const int lhi = lane >> 4;
  const int n0w = n0 + wv * 8;          // wave owns 8 nodes x 2 batches
  if (n0w >= NNODES) return;

  const unsigned short* __restrict__ xg = xbT2 + (size_t)g * NNODES * 64;
  const int moff = (l16 & 1) * 32 + lhi * 8;       // bl*32 + k-slice (bf16 units)
  const int boff = lane * 8;
  const int idxbase = (wv * 8 + (l16 >> 1)) * SEQ; // per-lane node's index row

  f32x4 acc[4];
#pragma unroll
  for (int o = 0; o < 4; ++o) {
    f32x4 z = {0.f, 0.f, 0.f, 0.f};
    acc[o] = z;
  }

#pragma unroll
  for (int kk = 0; kk < SEQ; ++kk) {
    const int gi = idx_lds[idxbase + kk];          // per-lane (8 distinct/wave)
    const bf16x8 af = *(const bf16x8*)&xg[(size_t)gi * 64 + moff];
    const bf16x8 b0 = *(const bf16x8*)&wlds[(kk * 4 + 0) * 512 + boff];
    const bf16x8 b1 = *(const bf16x8*)&wlds[(kk * 4 + 1) * 512 + boff];
    const bf16x8 b2 = *(const bf16x8*)&wlds[(kk * 4 + 2) * 512 + boff];
    const bf16x8 b3 = *(const bf16x8*)&wlds[(kk * 4 + 3) * 512 + boff];
    acc[0] = __builtin_amdgcn_mfma_f32_16x16x32_bf16(af, b0, acc[0], 0, 0, 0);
    acc[1] = __builtin_amdgcn_mfma_f32_16x16x32_bf16(af, b1, acc[1], 0, 0, 0);
    acc[2] = __builtin_amdgcn_mfma_f32_16x16x32_bf16(af, b2, acc[2], 0, 0, 0);
    acc[3] = __builtin_amdgcn_mfma_f32_16x16x32_bf16(af, b3, acc[3], 0, 0, 0);
  }

  // epilogue: D row m = lhi*4+reg -> node = n0w + (m>>1), bl = m&1.
  // reg pairs (0,1)/(2,3) share a node -> one cvt_pk u32 store each.
  unsigned* __restrict__ hg = hT + (size_t)g * NNODES * 64;
  const int nA = n0w + lhi * 2;
#pragma unroll
  for (int o = 0; o < 4; ++o) {
    const int oc = o * 16 + l16;
    const float bv = bias[oc];
    float v0 = acc[o][0] + bv, v1 = acc[o][1] + bv;
    float v2 = acc[o][2] + bv, v3 = acc[o][3] + bv;
    v0 = v0 > 0.f ? v0 : (__expf(v0) - 1.f);
    v1 = v1 > 0.f ? v1 : (__expf(v1) - 1.f);
    v2 = v2 > 0.f ? v2 : (__expf(v2) - 1.f);
    v3 = v3 > 0.f ? v3 : (__expf(v3) - 1.f);
    hg[(size_t)nA * 64 + oc]       = cvt_pk_bf16(v0, v1);
    hg[(size_t)(nA + 1) * 64 + oc] = cvt_pk_bf16(v2, v3);
  }
}

// ---- pool: wave per row; per entry 8x 256B-contiguous slice reads ----
__global__ __launch_bounds__(256) void pool_kernel(
    const unsigned* __restrict__ hT,        // [8][NNODES][64] u32
    const int* __restrict__ start,
    const int2* __restrict__ cvp,
    float* __restrict__ out)                // [BS][MPOOL][COUT]
{
  const int r = blockIdx.x * 4 + (threadIdx.x >> 6);
  const int lane = threadIdx.x & 63;       // lane = oc

  float acc[16];
#pragma unroll
  for (int b = 0; b < 16; ++b) acc[b] = 0.f;

  const int s = start[r], e = start[r + 1];
  int2 cv = (s < e) ? cvp[s] : make_int2(0, 0);
  for (int j = s; j < e; ++j) {
    const int2 cvn = (j + 1 < e) ? cvp[j + 1] : make_int2(0, 0);
    const int c = cv.x;
    const float v = __int_as_float(cv.y);
#pragma unroll
    for (int g = 0; g < 8; ++g) {
      const unsigned u = hT[((size_t)g * NNODES + c) * 64 + lane];
      acc[2 * g]     += v * bf2f((unsigned short)(u & 0xffff));
      acc[2 * g + 1] += v * bf2f((unsigned short)(u >> 16));
    }
    cv = cvn;
  }
#pragma unroll
  for (int b = 0; b < 16; ++b)
    out[((size_t)b * MPOOL + r) * COUT + lane] = acc[b];
}

// ---- fallback atomic scatter (small ws) ----
__global__ __launch_bounds__(256) void scatter_kernel(
    const unsigned* __restrict__ hT,
    const int* __restrict__ rows,
    const int* __restrict__ cols,
    const float* __restrict__ vals,
    float* __restrict__ out)
{
  const int gw = (int)((blockIdx.x * blockDim.x + threadIdx.x) >> 6);
  const int lane = threadIdx.x & 63;
  const int nw = (int)((gridDim.x * blockDim.x) >> 6);
  for (int t = gw; t < NNZ * BS; t += nw) {
    const int k = t >> 4;
    const int b = t & 15;
    const unsigned u = hT[((size_t)(b >> 1) * NNODES + cols[k]) * 64 + lane];
    const float hv = bf2f((unsigned short)((b & 1) ? (u >> 16) : (u & 0xffff)));
    atomicAdd(&out[((size_t)b * MPOOL + rows[k]) * COUT + lane], hv * vals[k]);
  }
}

extern "C" void kernel_launch(void* const* d_in, const int* in_sizes, int n_in,
                              void* d_out, int out_size, void* d_ws, size_t ws_size,
                              hipStream_t stream) {
  const float* x       = (const float*)d_in[0];
  const int*   indices = (const int*)d_in[1];
  const float* weight  = (const float*)d_in[2];
  const float* bias    = (const float*)d_in[3];
  const int*   trows   = (const int*)d_in[4];
  const int*   tcols   = (const int*)d_in[5];
  const float* tvals   = (const float*)d_in[6];
  float* out = (float*)d_out;

  char* w = (char*)d_ws;
  unsigned* hT         = (unsigned*)w;
  unsigned short* xbT2 = (unsigned short*)(w + H_BYTES);
  unsigned short* wf   = (unsigned short*)(w + H_BYTES + XB_BYTES);
  int2* cvp  = (int2*)(w + H_BYTES + XB_BYTES + WF_BYTES);
  int* start = (int*)(w + H_BYTES + XB_BYTES + WF_BYTES + CV_BYTES);
  int* cnt   = (int*)(w + H_BYTES + XB_BYTES + WF_BYTES + CV_BYTES + START_BYTES);
  int* cursor = cnt + MPOOL;

  const bool big_ws = (ws_size >=
      H_BYTES + XB_BYTES + WF_BYTES + CV_BYTES + START_BYTES + CNTCUR_BYTES);

  prep_kernel<<<XBLK + WBLK + ZBLK, 256, 0, stream>>>(x, weight, xbT2, wf, cnt);

  if (big_ws) {
    hist_kernel<<<(NNZ + 255) / 256, 256, 0, stream>>>(trows, cnt);
    scan_kernel<<<1, 256, 0, stream>>>(cnt, start);
    reorder_kernel<<<(NNZ + 255) / 256, 256, 0, stream>>>(trows, tcols, tvals,
                                                          start, cursor, cvp);
  }

  // 313 node-tiles x 8 batch-groups; bid&7 = g so each XCD stays on its slice
  gemm_elu_kernel<<<313 * 8, 512, 0, stream>>>(xbT2, indices, wf, bias, hT);

  if (big_ws) {
    pool_kernel<<<MPOOL / 4, 256, 0, stream>>>(hT, start, cvp, out);
  } else {
    hipMemsetAsync(d_out, 0, (size_t)out_size * sizeof(float), stream);
    scatter_kernel<<<4096, 256, 0, stream>>>(hT, trows, tcols, tvals, out);
  }
}